// Round 14
// baseline (294.577 us; speedup 1.0000x reference)
//
#include <hip/hip_runtime.h>
#include <hip/hip_fp16.h>
#include <math.h>

// GAT 2-layer, N=50000, E=800000 (+N self loops), IN=128, HID=32, HEADS=4, OUT=32
#define NN   50000
#define EE   800000
#define ETOT 850000          // EE + NN
#define NEG  0.2f
#define SCAN_BLOCKS ((NN + 255) / 256)   // 196

// -------- workspace layout (element offsets, 4B units; ints/halfs alias floats) --------
// zero-initialized region (one contiguous memset):
#define O_DEG    0           //    50,000  in-degree per node (int, EXCLUDING self-loop)
#define O_EASUM  50000       //         4  edge_attr sum (scalar)
#define ZERO_ELEMS 50004
// non-zeroed:
#define O_COEF   50004       //         8  coef1[4], coef2 at [4]
#define O_ROWPTR 50012       //    50,001  CSR row pointers (int)
#define O_CURSOR 100016      //    50,000  fill cursors (int)
#define O_BLKSUM 150016      //       256  per-block scan totals (int)
#define O_SLOT   150528      //   850,000  packed CSR slots: {src:16 | fp16(ea):16} (4B)
#define O_ASRC1  1850528     //   200,000  per-node src logits layer1 [N][4]
#define O_ADST1  2050528     //   200,000  per-node dst logits layer1 [N][4]
#define O_XLH    2250528     // 3,200,000  layer-1 features fp16 [N][128] (6.4M halfs)
#define O_OUT1   5450528     // 6,400,000  layer-1 agg output fp32 [N][128]
#define O_HLH    11850528    //   800,000  layer-2 features fp16 [N][32] (1.6M halfs)
#define O_ASRC2  12650528    //    50,000  per-node src logits layer2
#define O_ADST2  12700528    //    50,000  per-node dst logits layer2
#define WS_ELEMS 12750528    // ~51 MB

#define NODES_PER_GRP (NN / 8)                               // 6250 (NN % 8 == 0)

// ------ edge_attr sum + degree count, XCD-PARTITIONED by dst range + coef -------
// Round-13 analysis: 800K atomicAdd(deg + random_dst) from all 8 XCDs = the same
// cross-XCD line ping-pong that cost old k_fill 55-63 us (round-6 verified:
// WRITE_SIZE == stores*64B). Same fix as round-7's k_fill: group g = bid&7 (one
// XCD under round-robin dispatch; perf heuristic) counts ONLY dst in its range ->
// deg lines single-XCD-owned. ei-dst re-read 8x is L3-served (round-7 verified).
// ea-sum: g==0 blocks only (each edge exactly once). coef: block 0.
#define CNT_CHUNK  2048
#define CNT_NCHUNK ((EE + CNT_CHUNK - 1) / CNT_CHUNK)        // 391
__global__ __launch_bounds__(256) void k_ea_count(
    const float* __restrict__ ea, const int* __restrict__ ei,
    const float* __restrict__ lew1, const float* __restrict__ ae1,
    const float* __restrict__ lew2, const float* __restrict__ ae2,
    float* __restrict__ easum, int* __restrict__ deg,
    float* __restrict__ coef) {
  __shared__ float red[4];
  // block 0, threads 0-127: edge-coef dot products (tiny)
  if (blockIdx.x == 0 && threadIdx.x < 128) {
    int t = threadIdx.x;
    float p = lew1[t] * ae1[t];
    #pragma unroll
    for (int o = 16; o > 0; o >>= 1) p += __shfl_down(p, o, 32);
    if ((t & 31) == 0) coef[t >> 5] = p;
    if (t < 32) {
      float q = lew2[t] * ae2[t];
      #pragma unroll
      for (int o = 16; o > 0; o >>= 1) q += __shfl_down(q, o, 32);
      if (t == 0) coef[4] = q;
    }
  }
  const int g    = blockIdx.x & 7;            // dst group == XCD (heuristic)
  const int c    = blockIdx.x >> 3;           // edge chunk
  const int dlo  = g * NODES_PER_GRP;
  const int dhi  = dlo + NODES_PER_GRP;
  const int base = c * CNT_CHUNK;
  float s = 0.f;
  #pragma unroll
  for (int it = 0; it < CNT_CHUNK / 256; ++it) {
    const int e = base + it * 256 + threadIdx.x;
    if (e < EE) {
      int d = ei[EE + e];
      if (d >= dlo && d < dhi) atomicAdd(deg + d, 1);
      if (g == 0) s += ea[e];                 // each edge summed once
    }
  }
  if (g == 0) {
    #pragma unroll
    for (int o = 32; o > 0; o >>= 1) s += __shfl_down(s, o, 64);
    if ((threadIdx.x & 63) == 0) red[threadIdx.x >> 6] = s;
    __syncthreads();
    if (threadIdx.x == 0) atomicAdd(easum, red[0] + red[1] + red[2] + red[3]);
  }
}

// -------------------- multi-block exclusive scan of (deg+1) --------------------
__device__ __forceinline__ int wave_incl_scan(int v, int lane) {
  #pragma unroll
  for (int o = 1; o < 64; o <<= 1) {
    int u = __shfl_up(v, o, 64);
    if (lane >= o) v += u;
  }
  return v;
}

__global__ __launch_bounds__(256) void k_scan_blk(const int* __restrict__ deg,
                                                  int* __restrict__ rowptr,
                                                  int* __restrict__ blksum) {
  __shared__ int wsum[4];
  const int t = threadIdx.x;
  const int i = blockIdx.x * 256 + t;
  const int lane = t & 63, wv = t >> 6;
  int v = (i < NN) ? (deg[i] + 1) : 0;       // +1 = self-loop
  int incl = wave_incl_scan(v, lane);
  if (lane == 63) wsum[wv] = incl;
  __syncthreads();
  int off = 0;
  #pragma unroll
  for (int k = 0; k < 4; ++k) if (k < wv) off += wsum[k];
  incl += off;
  if (i < NN) rowptr[i] = incl - v;          // local exclusive
  if (t == 255) blksum[blockIdx.x] = incl;   // block total
}

// fused top-level scan + add: each block reduces blksum[0..bid) itself
// (196 L2-resident ints; no separate 1-block top-scan launch)
__global__ __launch_bounds__(256) void k_scan_add(int* __restrict__ rowptr,
                                                  int* __restrict__ cursor,
                                                  const int* __restrict__ blksum) {
  __shared__ int wsum[4];
  const int t = threadIdx.x;
  int v = (t < SCAN_BLOCKS && t < (int)blockIdx.x) ? blksum[t] : 0;
  #pragma unroll
  for (int o = 32; o > 0; o >>= 1) v += __shfl_down(v, o, 64);
  if ((t & 63) == 0) wsum[t >> 6] = v;
  __syncthreads();
  const int off = wsum[0] + wsum[1] + wsum[2] + wsum[3];
  const int i = blockIdx.x * 256 + t;
  if (i < NN) {
    int r = rowptr[i] + off;
    rowptr[i] = r;
    cursor[i] = r;
  }
  if (i == 0) rowptr[NN] = ETOT;
}

// fill CSR slots, XCD-partitioned by dst range (round-7 verified). Round-13:
// do NOT fuse with lin1 — same-grid fusion serializes by dispatch order and
// inflated FETCH to 50 MB (sum, not max). Keep separate.
#define FILL_CHUNK  2048
#define FILL_NCHUNK ((ETOT + FILL_CHUNK - 1) / FILL_CHUNK)   // 416
__global__ __launch_bounds__(256) void k_fill(
    const int* __restrict__ ei, const float* __restrict__ eattr,
    const float* __restrict__ easum, int* __restrict__ cursor,
    unsigned* __restrict__ slot) {
  const int g    = blockIdx.x & 7;            // dst group == XCD (heuristic)
  const int c    = blockIdx.x >> 3;           // edge chunk
  const int dlo  = g * NODES_PER_GRP;
  const int dhi  = dlo + NODES_PER_GRP;
  const int base = c * FILL_CHUNK;
  #pragma unroll
  for (int it = 0; it < FILL_CHUNK / 256; ++it) {
    const int e = base + it * 256 + threadIdx.x;
    if (e < ETOT) {
      int d = (e < EE) ? ei[EE + e] : (e - EE);
      if (d >= dlo && d < dhi) {
        int s; float ea;
        if (e < EE) { s = ei[e]; ea = eattr[e]; }
        else { s = d; ea = easum[0] * (1.f / EE); }
        int sl = atomicAdd(cursor + d, 1);
        unsigned hb = (unsigned)__half_as_ushort(__float2half_rn(ea));
        slot[sl] = (unsigned)s | (hb << 16);
      }
    }
  }
}

// 32 FMAs against one uniform W row of 32 floats
#define GEMM_STEP(WB, K, XS) {                                              \
    const float4* Wr = (const float4*)((WB) + (size_t)(K));                 \
    _Pragma("unroll")                                                       \
    for (int j4 = 0; j4 < 8; ++j4) {                                        \
      float4 wv = Wr[j4];                                                   \
      acc[j4 * 4 + 0] += (XS) * wv.x;                                       \
      acc[j4 * 4 + 1] += (XS) * wv.y;                                       \
      acc[j4 * 4 + 2] += (XS) * wv.z;                                       \
      acc[j4 * 4 + 3] += (XS) * wv.w;                                       \
    } }

// -------------------- layer-1 GEMM: xl(fp16) = x @ W1, plus per-node logits -------------
// Round-8 lesson: h must be PROVABLY scalar (readfirstlane) so W reads stay s_load.
// Round-10 verified: out of top-5; FETCH 12.8 MB; keep as-is.
#define L1_NB ((NN + 63) / 64)      // 782 node-blocks
__global__ __launch_bounds__(256) void k_lin1(
    const float* __restrict__ x, const float* __restrict__ W,
    const float* __restrict__ att_src, const float* __restrict__ att_dst,
    __half* __restrict__ xlh, float* __restrict__ asrc, float* __restrict__ adst) {
  const int h   = __builtin_amdgcn_readfirstlane(threadIdx.x >> 6);  // SGPR head id
  const int n   = blockIdx.x * 64 + (threadIdx.x & 63);
  const int nc  = n < NN ? n : NN - 1;
  const float4* xr = (const float4*)(x + (size_t)nc * 128);
  const float*  Wh = W + h * 32;              // scalar base -> s_load W rows
  float acc[32];
  #pragma unroll
  for (int j = 0; j < 32; ++j) acc[j] = 0.f;
  float4 xv = xr[0];
  for (int kt = 0; kt < 32; ++kt) {
    float4 cur = xv;
    if (kt < 31) xv = xr[kt + 1];             // prefetch next 16B of x
    GEMM_STEP(Wh, (kt * 4 + 0) * 128, cur.x);
    GEMM_STEP(Wh, (kt * 4 + 1) * 128, cur.y);
    GEMM_STEP(Wh, (kt * 4 + 2) * 128, cur.z);
    GEMM_STEP(Wh, (kt * 4 + 3) * 128, cur.w);
  }
  if (n < NN) {
    __align__(16) __half hbuf[32];
    #pragma unroll
    for (int j = 0; j < 32; ++j) hbuf[j] = __float2half_rn(acc[j]);
    float4* dst = (float4*)(xlh + (size_t)n * 128 + h * 32);   // 64 B, 16B-aligned
    #pragma unroll
    for (int i = 0; i < 4; ++i) dst[i] = ((const float4*)hbuf)[i];
    float ss = 0.f, sd = 0.f;
    #pragma unroll
    for (int j = 0; j < 32; ++j) {
      ss += acc[j] * att_src[h * 32 + j];     // scalar loads
      sd += acc[j] * att_dst[h * 32 + j];
    }
    asrc[n * 4 + h] = ss;
    adst[n * 4 + h] = sd;
  }
}

// -------------------- layer-1 aggregation (fused softmax), batch-4 pipelined ------------
// half-wave per node, lane = 4 channels; per batch: 4 packed slot loads -> 4 indep
// metadata loads + 4 indep row gathers -> math. Tail masked branch-free.
__global__ __launch_bounds__(256) void k_agg1(
    const int* __restrict__ rowptr, const unsigned* __restrict__ slot,
    const float* __restrict__ asrc, const float* __restrict__ adst,
    const float* __restrict__ coef, const __half* __restrict__ xlh,
    float* __restrict__ out1) {
  int n = blockIdx.x * 8 + (threadIdx.x >> 5);
  if (n >= NN) return;
  int l = threadIdx.x & 31;
  int c4 = l << 2;                    // 4 channels per lane, 32 lanes = 128 ch
  int h = l >> 3;                     // head of this channel group
  float cf = coef[h];
  float ad = adst[(size_t)n * 4 + h];
  int r0 = rowptr[n], r1 = rowptr[n + 1];   // r1 > r0 (self-loop)
  float a0 = 0.f, a1 = 0.f, a2 = 0.f, a3 = 0.f, den = 0.f;
  for (int j = r0; j < r1; j += 4) {
    unsigned sd[4]; float asv[4]; uint2 raw[4];
    #pragma unroll
    for (int k = 0; k < 4; ++k) {
      int jj = (j + k < r1) ? (j + k) : (r1 - 1);
      sd[k] = slot[jj];
    }
    #pragma unroll
    for (int k = 0; k < 4; ++k) {
      int sn = (int)(sd[k] & 0xFFFFu);
      asv[k] = asrc[(size_t)sn * 4 + h];
      raw[k] = *(const uint2*)(xlh + (size_t)sn * 128 + c4);   // 4 halfs
    }
    #pragma unroll
    for (int k = 0; k < 4; ++k) {
      float eav = __half2float(__ushort_as_half((unsigned short)(sd[k] >> 16)));
      float alpha = asv[k] + ad + eav * cf;
      alpha = alpha > 0.f ? alpha : NEG * alpha;
      float ex = (j + k < r1) ? __expf(alpha) : 0.f;   // tail mask
      __half2 p0, p1;
      *(unsigned int*)&p0 = raw[k].x;
      *(unsigned int*)&p1 = raw[k].y;
      float2 f0 = __half22float2(p0), f1 = __half22float2(p1);
      a0 += ex * f0.x;
      a1 += ex * f0.y;
      a2 += ex * f1.x;
      a3 += ex * f1.y;
      den += ex;
    }
  }
  float inv = 1.f / den;
  *(float4*)(out1 + (size_t)n * 128 + c4) = make_float4(a0 * inv, a1 * inv, a2 * inv, a3 * inv);
}

// -------------------- layer-2 GEMM: hl(fp16) = elu(out1+bias1) @ W2, plus logits --------
// Round-12 verified: 4 threads/node (8 cols each) lifted occupancy; k_lin2 left top-5.
__global__ __launch_bounds__(256) void k_lin2(
    const float* __restrict__ out1, const float* __restrict__ bias1,
    const float* __restrict__ W2,
    const float* __restrict__ as2w, const float* __restrict__ ad2w,
    __half* __restrict__ hlh, float* __restrict__ asrc2, float* __restrict__ adst2) {
  const int q  = threadIdx.x & 3;            // column quarter: cols [q*8, q*8+8)
  const int n  = blockIdx.x * 64 + (threadIdx.x >> 2);
  const int nc = n < NN ? n : NN - 1;
  const float4* xr = (const float4*)(out1 + (size_t)nc * 128);
  const float4* br = (const float4*)bias1;   // uniform
  const float4* W8 = (const float4*)(W2 + q * 8);   // per-lane col base (L1-resident)
  float acc[8];
  #pragma unroll
  for (int j = 0; j < 8; ++j) acc[j] = 0.f;
  float4 xv = xr[0];
  for (int kt = 0; kt < 32; ++kt) {
    float4 cur = xv;
    if (kt < 31) xv = xr[kt + 1];
    float4 b = br[kt];                       // uniform
    cur.x += b.x; cur.y += b.y; cur.z += b.z; cur.w += b.w;
    cur.x = cur.x > 0.f ? cur.x : (expf(cur.x) - 1.f);   // ELU
    cur.y = cur.y > 0.f ? cur.y : (expf(cur.y) - 1.f);
    cur.z = cur.z > 0.f ? cur.z : (expf(cur.z) - 1.f);
    cur.w = cur.w > 0.f ? cur.w : (expf(cur.w) - 1.f);
    #pragma unroll
    for (int kk = 0; kk < 4; ++kk) {
      const float xs = (kk == 0) ? cur.x : (kk == 1) ? cur.y : (kk == 2) ? cur.z : cur.w;
      const float4 w0 = W8[(kt * 4 + kk) * 8 + 0];   // W2[(kt*4+kk)*32 + q*8 .. +4)
      const float4 w1 = W8[(kt * 4 + kk) * 8 + 1];   // .. +4..8)
      acc[0] += xs * w0.x; acc[1] += xs * w0.y;
      acc[2] += xs * w0.z; acc[3] += xs * w0.w;
      acc[4] += xs * w1.x; acc[5] += xs * w1.y;
      acc[6] += xs * w1.z; acc[7] += xs * w1.w;
    }
  }
  // partial logits over the 8 owned cols, reduced across the 4-lane node group
  float ps = 0.f, pd = 0.f;
  #pragma unroll
  for (int j = 0; j < 8; ++j) {
    ps += acc[j] * as2w[q * 8 + j];
    pd += acc[j] * ad2w[q * 8 + j];
  }
  ps += __shfl_xor(ps, 1, 64); ps += __shfl_xor(ps, 2, 64);
  pd += __shfl_xor(pd, 1, 64); pd += __shfl_xor(pd, 2, 64);
  if (n < NN) {
    __align__(16) __half hbuf[8];
    #pragma unroll
    for (int j = 0; j < 8; ++j) hbuf[j] = __float2half_rn(acc[j]);
    *(float4*)(hlh + (size_t)n * 32 + q * 8) = *(const float4*)hbuf;   // 16 B
    if (q == 0) {
      asrc2[n] = ps;
      adst2[n] = pd;
    }
  }
}

// -------------------- layer-2 aggregation (fused softmax), batch-4 pipelined ------------
__global__ __launch_bounds__(256) void k_agg2(
    const int* __restrict__ rowptr, const unsigned* __restrict__ slot,
    const float* __restrict__ asrc2, const float* __restrict__ adst2,
    const float* __restrict__ coef, const __half* __restrict__ hlh,
    const float* __restrict__ bias2, float* __restrict__ out) {
  int n = blockIdx.x * 32 + (threadIdx.x >> 3);
  if (n >= NN) return;
  int c4 = (threadIdx.x & 7) << 2;
  float cf = coef[4];
  float ad = adst2[n];
  int r0 = rowptr[n], r1 = rowptr[n + 1];
  float a0 = 0.f, a1 = 0.f, a2 = 0.f, a3 = 0.f, den = 0.f;
  for (int j = r0; j < r1; j += 4) {
    unsigned sd[4]; float asv[4]; uint2 raw[4];
    #pragma unroll
    for (int k = 0; k < 4; ++k) {
      int jj = (j + k < r1) ? (j + k) : (r1 - 1);
      sd[k] = slot[jj];
    }
    #pragma unroll
    for (int k = 0; k < 4; ++k) {
      int sn = (int)(sd[k] & 0xFFFFu);
      asv[k] = asrc2[sn];
      raw[k] = *(const uint2*)(hlh + (size_t)sn * 32 + c4);   // 4 halfs
    }
    #pragma unroll
    for (int k = 0; k < 4; ++k) {
      float eav = __half2float(__ushort_as_half((unsigned short)(sd[k] >> 16)));
      float alpha = asv[k] + ad + eav * cf;
      alpha = alpha > 0.f ? alpha : NEG * alpha;
      float ex = (j + k < r1) ? __expf(alpha) : 0.f;   // tail mask
      __half2 p0, p1;
      *(unsigned int*)&p0 = raw[k].x;
      *(unsigned int*)&p1 = raw[k].y;
      float2 f0 = __half22float2(p0), f1 = __half22float2(p1);
      a0 += ex * f0.x;
      a1 += ex * f0.y;
      a2 += ex * f1.x;
      a3 += ex * f1.y;
      den += ex;
    }
  }
  float inv = 1.f / den;
  float4 b = *(const float4*)(bias2 + c4);
  *(float4*)(out + (size_t)n * 32 + c4) =
      make_float4(a0 * inv + b.x, a1 * inv + b.y, a2 * inv + b.z, a3 * inv + b.w);
}

extern "C" void kernel_launch(void* const* d_in, const int* in_sizes, int n_in,
                              void* d_out, int out_size, void* d_ws, size_t ws_size,
                              hipStream_t stream) {
  const float* x        = (const float*)d_in[0];
  const int*   ei       = (const int*)d_in[1];
  const float* eattr    = (const float*)d_in[2];
  const float* lin1_w   = (const float*)d_in[3];
  const float* att1_src = (const float*)d_in[4];
  const float* att1_dst = (const float*)d_in[5];
  const float* lin1_ew  = (const float*)d_in[6];
  const float* att1_e   = (const float*)d_in[7];
  const float* bias1    = (const float*)d_in[8];
  const float* lin2_w   = (const float*)d_in[9];
  const float* att2_src = (const float*)d_in[10];
  const float* att2_dst = (const float*)d_in[11];
  const float* lin2_ew  = (const float*)d_in[12];
  const float* att2_e   = (const float*)d_in[13];
  const float* bias2    = (const float*)d_in[14];
  float* out = (float*)d_out;
  float* ws  = (float*)d_ws;
  int*   wsi = (int*)d_ws;

  int*      deg     = wsi + O_DEG;
  float*    easum   = ws + O_EASUM;
  float*    coef    = ws + O_COEF;
  int*      rowptr  = wsi + O_ROWPTR;
  int*      cursor  = wsi + O_CURSOR;
  int*      blksum  = wsi + O_BLKSUM;
  unsigned* slot    = (unsigned*)(ws + O_SLOT);
  float*    asrc1   = ws + O_ASRC1;
  float*    adst1   = ws + O_ADST1;
  __half*   xlh     = (__half*)(ws + O_XLH);
  float*    out1    = ws + O_OUT1;
  __half*   hlh     = (__half*)(ws + O_HLH);
  float*    asrc2   = ws + O_ASRC2;
  float*    adst2   = ws + O_ADST2;

  // zero deg/easum (ws poisoned 0xAA each call)
  hipMemsetAsync(ws, 0, (size_t)ZERO_ELEMS * sizeof(float), stream);

  // degree count + ea sum + coef, XCD-partitioned atomics
  k_ea_count<<<CNT_NCHUNK * 8, 256, 0, stream>>>(eattr, ei, lin1_ew, att1_e,
                                                 lin2_ew, att2_e, easum, deg, coef);

  // CSR build (dst-sorted): multi-block scan (top-level scan fused into add)
  k_scan_blk<<<SCAN_BLOCKS, 256, 0, stream>>>(deg, rowptr, blksum);
  k_scan_add<<<SCAN_BLOCKS, 256, 0, stream>>>(rowptr, cursor, blksum);
  k_fill<<<FILL_NCHUNK * 8, 256, 0, stream>>>(ei, eattr, easum, cursor, slot);

  // layer 1
  k_lin1<<<L1_NB, 256, 0, stream>>>(x, lin1_w, att1_src, att1_dst, xlh, asrc1, adst1);
  k_agg1<<<(NN + 7) / 8, 256, 0, stream>>>(rowptr, slot, asrc1, adst1, coef, xlh, out1);

  // layer 2: 4 threads/node, 64 nodes per 256-thread block
  k_lin2<<<(NN + 63) / 64, 256, 0, stream>>>(out1, bias1, lin2_w, att2_src, att2_dst, hlh, asrc2, adst2);
  k_agg2<<<(NN + 31) / 32, 256, 0, stream>>>(rowptr, slot, asrc2, adst2, coef, hlh, bias2, out);
}

// Round 15
// 283.446 us; speedup vs baseline: 1.0393x; 1.0393x over previous
//
#include <hip/hip_runtime.h>
#include <hip/hip_fp16.h>
#include <math.h>

// GAT 2-layer, N=50000, E=800000 (+N self loops), IN=128, HID=32, HEADS=4, OUT=32
#define NN   50000
#define EE   800000
#define ETOT 850000          // EE + NN
#define NEG  0.2f
#define SCAN_BLOCKS ((NN + 255) / 256)   // 196

// -------- workspace layout (element offsets, 4B units; ints/halfs alias floats) --------
// zero-initialized region (one contiguous memset):
#define O_DEG    0           //    50,000  in-degree per node (int, EXCLUDING self-loop)
#define O_EASUM  50000       //         4  edge_attr sum (scalar)
#define ZERO_ELEMS 50004
// non-zeroed:
#define O_COEF   50004       //         8  coef1[4], coef2 at [4]
#define O_ROWPTR 50012       //    50,001  CSR row pointers (int)
#define O_CURSOR 100016      //    50,000  fill cursors (int)
#define O_BLKSUM 150016      //       256  per-block scan totals (int)
#define O_SLOT   150528      //   850,000  packed CSR slots: {src:16 | fp16(ea):16} (4B)
#define O_ASRC1  1850528     //   200,000  per-node src logits layer1 [N][4]
#define O_ADST1  2050528     //   200,000  per-node dst logits layer1 [N][4]
#define O_XLH    2250528     // 3,200,000  layer-1 features fp16 [N][128] (6.4M halfs)
#define O_HLH    11850528    //   800,000  layer-2 features fp16 [N][32] (1.6M halfs)
#define O_ASRC2  12650528    //    50,000  per-node src logits layer2
#define O_ADST2  12700528    //    50,000  per-node dst logits layer2
#define WS_ELEMS 12750528    // ~51 MB

#define NODES_PER_GRP (NN / 8)                               // 6250 (NN % 8 == 0)

// ------ fused: edge_attr sum + degree count (real edges only) + coef precompute -------
// (round-12 form — round-14's XCD-partitioned variant was neutral-to-negative)
__global__ void k_ea_count(const float* __restrict__ ea, const int* __restrict__ ei,
                           const float* __restrict__ lew1, const float* __restrict__ ae1,
                           const float* __restrict__ lew2, const float* __restrict__ ae2,
                           float* __restrict__ easum, int* __restrict__ deg,
                           float* __restrict__ coef) {
  // block 0, threads 0-127: edge-coef dot products (tiny, overlapped with edge loop)
  if (blockIdx.x == 0 && threadIdx.x < 128) {
    int t = threadIdx.x;
    float p = lew1[t] * ae1[t];
    #pragma unroll
    for (int o = 16; o > 0; o >>= 1) p += __shfl_down(p, o, 32);
    if ((t & 31) == 0) coef[t >> 5] = p;
    if (t < 32) {
      float q = lew2[t] * ae2[t];
      #pragma unroll
      for (int o = 16; o > 0; o >>= 1) q += __shfl_down(q, o, 32);
      if (t == 0) coef[4] = q;
    }
  }
  __shared__ float red[4];
  float s = 0.f;
  int stride = gridDim.x * blockDim.x;
  for (int i = blockIdx.x * blockDim.x + threadIdx.x; i < EE; i += stride) {
    s += ea[i];
    atomicAdd(deg + ei[EE + i], 1);
  }
  #pragma unroll
  for (int o = 32; o > 0; o >>= 1) s += __shfl_down(s, o, 64);
  if ((threadIdx.x & 63) == 0) red[threadIdx.x >> 6] = s;
  __syncthreads();
  if (threadIdx.x == 0) atomicAdd(easum, red[0] + red[1] + red[2] + red[3]);
}

// -------------------- multi-block exclusive scan of (deg+1) --------------------
__device__ __forceinline__ int wave_incl_scan(int v, int lane) {
  #pragma unroll
  for (int o = 1; o < 64; o <<= 1) {
    int u = __shfl_up(v, o, 64);
    if (lane >= o) v += u;
  }
  return v;
}

__global__ __launch_bounds__(256) void k_scan_blk(const int* __restrict__ deg,
                                                  int* __restrict__ rowptr,
                                                  int* __restrict__ blksum) {
  __shared__ int wsum[4];
  const int t = threadIdx.x;
  const int i = blockIdx.x * 256 + t;
  const int lane = t & 63, wv = t >> 6;
  int v = (i < NN) ? (deg[i] + 1) : 0;       // +1 = self-loop
  int incl = wave_incl_scan(v, lane);
  if (lane == 63) wsum[wv] = incl;
  __syncthreads();
  int off = 0;
  #pragma unroll
  for (int k = 0; k < 4; ++k) if (k < wv) off += wsum[k];
  incl += off;
  if (i < NN) rowptr[i] = incl - v;          // local exclusive
  if (t == 255) blksum[blockIdx.x] = incl;   // block total
}

// fused top-level scan + add: each block reduces blksum[0..bid) itself
// (196 L2-resident ints; no separate 1-block top-scan launch)
__global__ __launch_bounds__(256) void k_scan_add(int* __restrict__ rowptr,
                                                  int* __restrict__ cursor,
                                                  const int* __restrict__ blksum) {
  __shared__ int wsum[4];
  const int t = threadIdx.x;
  int v = (t < SCAN_BLOCKS && t < (int)blockIdx.x) ? blksum[t] : 0;
  #pragma unroll
  for (int o = 32; o > 0; o >>= 1) v += __shfl_down(v, o, 64);
  if ((t & 63) == 0) wsum[t >> 6] = v;
  __syncthreads();
  const int off = wsum[0] + wsum[1] + wsum[2] + wsum[3];
  const int i = blockIdx.x * 256 + t;
  if (i < NN) {
    int r = rowptr[i] + off;
    rowptr[i] = r;
    cursor[i] = r;
  }
  if (i == 0) rowptr[NN] = ETOT;
}

// fill CSR slots, XCD-partitioned by dst range (round-7 verified). Round-13:
// do NOT fuse with lin1 — same-grid fusion serializes by dispatch order.
#define FILL_CHUNK  2048
#define FILL_NCHUNK ((ETOT + FILL_CHUNK - 1) / FILL_CHUNK)   // 416
__global__ __launch_bounds__(256) void k_fill(
    const int* __restrict__ ei, const float* __restrict__ eattr,
    const float* __restrict__ easum, int* __restrict__ cursor,
    unsigned* __restrict__ slot) {
  const int g    = blockIdx.x & 7;            // dst group == XCD (heuristic)
  const int c    = blockIdx.x >> 3;           // edge chunk
  const int dlo  = g * NODES_PER_GRP;
  const int dhi  = dlo + NODES_PER_GRP;
  const int base = c * FILL_CHUNK;
  #pragma unroll
  for (int it = 0; it < FILL_CHUNK / 256; ++it) {
    const int e = base + it * 256 + threadIdx.x;
    if (e < ETOT) {
      int d = (e < EE) ? ei[EE + e] : (e - EE);
      if (d >= dlo && d < dhi) {
        int s; float ea;
        if (e < EE) { s = ei[e]; ea = eattr[e]; }
        else { s = d; ea = easum[0] * (1.f / EE); }
        int sl = atomicAdd(cursor + d, 1);
        unsigned hb = (unsigned)__half_as_ushort(__float2half_rn(ea));
        slot[sl] = (unsigned)s | (hb << 16);
      }
    }
  }
}

// 32 FMAs against one uniform W row of 32 floats
#define GEMM_STEP(WB, K, XS) {                                              \
    const float4* Wr = (const float4*)((WB) + (size_t)(K));                 \
    _Pragma("unroll")                                                       \
    for (int j4 = 0; j4 < 8; ++j4) {                                        \
      float4 wv = Wr[j4];                                                   \
      acc[j4 * 4 + 0] += (XS) * wv.x;                                       \
      acc[j4 * 4 + 1] += (XS) * wv.y;                                       \
      acc[j4 * 4 + 2] += (XS) * wv.z;                                       \
      acc[j4 * 4 + 3] += (XS) * wv.w;                                       \
    } }

// -------------------- layer-1 GEMM: xl(fp16) = x @ W1, plus per-node logits -------------
// Round-8 lesson: h must be PROVABLY scalar (readfirstlane) so W reads stay s_load.
#define L1_NB ((NN + 63) / 64)      // 782 node-blocks
__global__ __launch_bounds__(256) void k_lin1(
    const float* __restrict__ x, const float* __restrict__ W,
    const float* __restrict__ att_src, const float* __restrict__ att_dst,
    __half* __restrict__ xlh, float* __restrict__ asrc, float* __restrict__ adst) {
  const int h   = __builtin_amdgcn_readfirstlane(threadIdx.x >> 6);  // SGPR head id
  const int n   = blockIdx.x * 64 + (threadIdx.x & 63);
  const int nc  = n < NN ? n : NN - 1;
  const float4* xr = (const float4*)(x + (size_t)nc * 128);
  const float*  Wh = W + h * 32;              // scalar base -> s_load W rows
  float acc[32];
  #pragma unroll
  for (int j = 0; j < 32; ++j) acc[j] = 0.f;
  float4 xv = xr[0];
  for (int kt = 0; kt < 32; ++kt) {
    float4 cur = xv;
    if (kt < 31) xv = xr[kt + 1];             // prefetch next 16B of x
    GEMM_STEP(Wh, (kt * 4 + 0) * 128, cur.x);
    GEMM_STEP(Wh, (kt * 4 + 1) * 128, cur.y);
    GEMM_STEP(Wh, (kt * 4 + 2) * 128, cur.z);
    GEMM_STEP(Wh, (kt * 4 + 3) * 128, cur.w);
  }
  if (n < NN) {
    __align__(16) __half hbuf[32];
    #pragma unroll
    for (int j = 0; j < 32; ++j) hbuf[j] = __float2half_rn(acc[j]);
    float4* dst = (float4*)(xlh + (size_t)n * 128 + h * 32);   // 64 B, 16B-aligned
    #pragma unroll
    for (int i = 0; i < 4; ++i) dst[i] = ((const float4*)hbuf)[i];
    float ss = 0.f, sd = 0.f;
    #pragma unroll
    for (int j = 0; j < 32; ++j) {
      ss += acc[j] * att_src[h * 32 + j];     // scalar loads
      sd += acc[j] * att_dst[h * 32 + j];
    }
    asrc[n * 4 + h] = ss;
    adst[n * 4 + h] = sd;
  }
}

// --------- FUSED: layer-1 aggregation + layer-2 GEMM (lin2 folded in) ---------
// Round-14 theory: agg1 ends with the node's full 128-ch row spread across its
// half-wave; old k_lin2 re-read it from HBM (out1 25.6MB W + 25.6MB R) just for a
// 128x32 GEMM. Fold it in: edge loop unchanged; then ELU(row+bias1) -> LDS
// (512B/node, wave-synchronous, no barrier); each of the 32 lanes computes one
// output col (128 FMA vs L1-resident W2), stores hlh, and layer-2 logits reduce
// via shfl_xor. Deletes the lin2 launch + all out1 traffic; GEMM VALU work hides
// under the gather latency (agg1 was gather-bound, VALU idle).
__global__ __launch_bounds__(256) void k_agg1l2(
    const int* __restrict__ rowptr, const unsigned* __restrict__ slot,
    const float* __restrict__ asrc, const float* __restrict__ adst,
    const float* __restrict__ coef, const __half* __restrict__ xlh,
    const float* __restrict__ bias1, const float* __restrict__ W2,
    const float* __restrict__ as2w, const float* __restrict__ ad2w,
    __half* __restrict__ hlh, float* __restrict__ asrc2, float* __restrict__ adst2) {
  __shared__ float rowbuf[8][132];    // +4 pad: col k of node nl at bank (nl*132+k)%32
  int nl = threadIdx.x >> 5;          // node slot in block (0..7)
  int n = blockIdx.x * 8 + nl;
  if (n >= NN) return;
  int l = threadIdx.x & 31;
  int c4 = l << 2;                    // 4 channels per lane, 32 lanes = 128 ch
  int h = l >> 3;                     // head of this channel group
  float cf = coef[h];
  float ad = adst[(size_t)n * 4 + h];
  int r0 = rowptr[n], r1 = rowptr[n + 1];   // r1 > r0 (self-loop)
  float a0 = 0.f, a1 = 0.f, a2 = 0.f, a3 = 0.f, den = 0.f;
  for (int j = r0; j < r1; j += 4) {
    unsigned sd[4]; float asv[4]; uint2 raw[4];
    #pragma unroll
    for (int k = 0; k < 4; ++k) {
      int jj = (j + k < r1) ? (j + k) : (r1 - 1);
      sd[k] = slot[jj];
    }
    #pragma unroll
    for (int k = 0; k < 4; ++k) {
      int sn = (int)(sd[k] & 0xFFFFu);
      asv[k] = asrc[(size_t)sn * 4 + h];
      raw[k] = *(const uint2*)(xlh + (size_t)sn * 128 + c4);   // 4 halfs
    }
    #pragma unroll
    for (int k = 0; k < 4; ++k) {
      float eav = __half2float(__ushort_as_half((unsigned short)(sd[k] >> 16)));
      float alpha = asv[k] + ad + eav * cf;
      alpha = alpha > 0.f ? alpha : NEG * alpha;
      float ex = (j + k < r1) ? __expf(alpha) : 0.f;   // tail mask
      __half2 p0, p1;
      *(unsigned int*)&p0 = raw[k].x;
      *(unsigned int*)&p1 = raw[k].y;
      float2 f0 = __half22float2(p0), f1 = __half22float2(p1);
      a0 += ex * f0.x;
      a1 += ex * f0.y;
      a2 += ex * f1.x;
      a3 += ex * f1.y;
      den += ex;
    }
  }
  float inv = 1.f / den;
  // ELU(row + bias1) -> LDS (wave-synchronous: same wave writes then reads)
  float4 b = *(const float4*)(bias1 + c4);
  float v0 = a0 * inv + b.x, v1 = a1 * inv + b.y;
  float v2 = a2 * inv + b.z, v3 = a3 * inv + b.w;
  v0 = v0 > 0.f ? v0 : (expf(v0) - 1.f);
  v1 = v1 > 0.f ? v1 : (expf(v1) - 1.f);
  v2 = v2 > 0.f ? v2 : (expf(v2) - 1.f);
  v3 = v3 > 0.f ? v3 : (expf(v3) - 1.f);
  rowbuf[nl][c4 + 0] = v0;
  rowbuf[nl][c4 + 1] = v1;
  rowbuf[nl][c4 + 2] = v2;
  rowbuf[nl][c4 + 3] = v3;
  // layer-2 GEMM: lane = output col; row broadcast from LDS, W2 L1-resident
  const int col = l;
  const float* rw = rowbuf[nl];
  float hsum = 0.f;
  #pragma unroll 4
  for (int k = 0; k < 128; ++k) hsum += rw[k] * W2[k * 32 + col];
  hlh[(size_t)n * 32 + col] = __float2half_rn(hsum);
  float ps = hsum * as2w[col];
  float pd = hsum * ad2w[col];
  #pragma unroll
  for (int o = 1; o < 32; o <<= 1) {   // xor<32 stays within the half-wave
    ps += __shfl_xor(ps, o, 64);
    pd += __shfl_xor(pd, o, 64);
  }
  if (l == 0) {
    asrc2[n] = ps;
    adst2[n] = pd;
  }
}

// -------------------- layer-2 aggregation (fused softmax), batch-4 pipelined ------------
__global__ __launch_bounds__(256) void k_agg2(
    const int* __restrict__ rowptr, const unsigned* __restrict__ slot,
    const float* __restrict__ asrc2, const float* __restrict__ adst2,
    const float* __restrict__ coef, const __half* __restrict__ hlh,
    const float* __restrict__ bias2, float* __restrict__ out) {
  int n = blockIdx.x * 32 + (threadIdx.x >> 3);
  if (n >= NN) return;
  int c4 = (threadIdx.x & 7) << 2;
  float cf = coef[4];
  float ad = adst2[n];
  int r0 = rowptr[n], r1 = rowptr[n + 1];
  float a0 = 0.f, a1 = 0.f, a2 = 0.f, a3 = 0.f, den = 0.f;
  for (int j = r0; j < r1; j += 4) {
    unsigned sd[4]; float asv[4]; uint2 raw[4];
    #pragma unroll
    for (int k = 0; k < 4; ++k) {
      int jj = (j + k < r1) ? (j + k) : (r1 - 1);
      sd[k] = slot[jj];
    }
    #pragma unroll
    for (int k = 0; k < 4; ++k) {
      int sn = (int)(sd[k] & 0xFFFFu);
      asv[k] = asrc2[sn];
      raw[k] = *(const uint2*)(hlh + (size_t)sn * 32 + c4);   // 4 halfs
    }
    #pragma unroll
    for (int k = 0; k < 4; ++k) {
      float eav = __half2float(__ushort_as_half((unsigned short)(sd[k] >> 16)));
      float alpha = asv[k] + ad + eav * cf;
      alpha = alpha > 0.f ? alpha : NEG * alpha;
      float ex = (j + k < r1) ? __expf(alpha) : 0.f;   // tail mask
      __half2 p0, p1;
      *(unsigned int*)&p0 = raw[k].x;
      *(unsigned int*)&p1 = raw[k].y;
      float2 f0 = __half22float2(p0), f1 = __half22float2(p1);
      a0 += ex * f0.x;
      a1 += ex * f0.y;
      a2 += ex * f1.x;
      a3 += ex * f1.y;
      den += ex;
    }
  }
  float inv = 1.f / den;
  float4 b = *(const float4*)(bias2 + c4);
  *(float4*)(out + (size_t)n * 32 + c4) =
      make_float4(a0 * inv + b.x, a1 * inv + b.y, a2 * inv + b.z, a3 * inv + b.w);
}

extern "C" void kernel_launch(void* const* d_in, const int* in_sizes, int n_in,
                              void* d_out, int out_size, void* d_ws, size_t ws_size,
                              hipStream_t stream) {
  const float* x        = (const float*)d_in[0];
  const int*   ei       = (const int*)d_in[1];
  const float* eattr    = (const float*)d_in[2];
  const float* lin1_w   = (const float*)d_in[3];
  const float* att1_src = (const float*)d_in[4];
  const float* att1_dst = (const float*)d_in[5];
  const float* lin1_ew  = (const float*)d_in[6];
  const float* att1_e   = (const float*)d_in[7];
  const float* bias1    = (const float*)d_in[8];
  const float* lin2_w   = (const float*)d_in[9];
  const float* att2_src = (const float*)d_in[10];
  const float* att2_dst = (const float*)d_in[11];
  const float* lin2_ew  = (const float*)d_in[12];
  const float* att2_e   = (const float*)d_in[13];
  const float* bias2    = (const float*)d_in[14];
  float* out = (float*)d_out;
  float* ws  = (float*)d_ws;
  int*   wsi = (int*)d_ws;

  int*      deg     = wsi + O_DEG;
  float*    easum   = ws + O_EASUM;
  float*    coef    = ws + O_COEF;
  int*      rowptr  = wsi + O_ROWPTR;
  int*      cursor  = wsi + O_CURSOR;
  int*      blksum  = wsi + O_BLKSUM;
  unsigned* slot    = (unsigned*)(ws + O_SLOT);
  float*    asrc1   = ws + O_ASRC1;
  float*    adst1   = ws + O_ADST1;
  __half*   xlh     = (__half*)(ws + O_XLH);
  __half*   hlh     = (__half*)(ws + O_HLH);
  float*    asrc2   = ws + O_ASRC2;
  float*    adst2   = ws + O_ADST2;

  // zero deg/easum (ws poisoned 0xAA each call)
  hipMemsetAsync(ws, 0, (size_t)ZERO_ELEMS * sizeof(float), stream);

  k_ea_count<<<256, 256, 0, stream>>>(eattr, ei, lin1_ew, att1_e, lin2_ew, att2_e,
                                      easum, deg, coef);

  // CSR build (dst-sorted): multi-block scan (top-level scan fused into add)
  k_scan_blk<<<SCAN_BLOCKS, 256, 0, stream>>>(deg, rowptr, blksum);
  k_scan_add<<<SCAN_BLOCKS, 256, 0, stream>>>(rowptr, cursor, blksum);
  k_fill<<<FILL_NCHUNK * 8, 256, 0, stream>>>(ei, eattr, easum, cursor, slot);

  // layer 1
  k_lin1<<<L1_NB, 256, 0, stream>>>(x, lin1_w, att1_src, att1_dst, xlh, asrc1, adst1);

  // fused layer-1 aggregation + layer-2 GEMM (out1 never materialized)
  k_agg1l2<<<(NN + 7) / 8, 256, 0, stream>>>(rowptr, slot, asrc1, adst1, coef, xlh,
                                             bias1, lin2_w, att2_src, att2_dst,
                                             hlh, asrc2, adst2);

  k_agg2<<<(NN + 31) / 32, 256, 0, stream>>>(rowptr, slot, asrc2, adst2, coef, hlh, bias2, out);
}

// Round 16
// 282.752 us; speedup vs baseline: 1.0418x; 1.0025x over previous
//
#include <hip/hip_runtime.h>
#include <hip/hip_fp16.h>
#include <math.h>

// GAT 2-layer, N=50000, E=800000 (+N self loops), IN=128, HID=32, HEADS=4, OUT=32
#define NN   50000
#define EE   800000
#define ETOT 850000          // EE + NN
#define NEG  0.2f
#define SCAN_BLOCKS ((NN + 255) / 256)   // 196

// -------- workspace layout (element offsets, 4B units; ints/halfs alias floats) --------
// zero-initialized region (one contiguous memset):
#define O_DEG    0           //    50,000  in-degree per node (int, EXCLUDING self-loop)
#define O_EASUM  50000       //         4  edge_attr sum (scalar)
#define ZERO_ELEMS 50004
// non-zeroed:
#define O_COEF   50004       //         8  coef1[4], coef2 at [4]
#define O_ROWPTR 50012       //    50,001  CSR row pointers (int)
#define O_CURSOR 100016      //    50,000  fill cursors (int)
#define O_BLKSUM 150016      //       256  per-block scan totals (int)
#define O_SLOT   150528      //   850,000  packed CSR slots: {src:16 | fp16(ea):16} (4B)
#define O_ASRC1  1850528     //   200,000  per-node src logits layer1 [N][4]
#define O_ADST1  2050528     //   200,000  per-node dst logits layer1 [N][4]
#define O_XLH    2250528     // 3,200,000  layer-1 features fp16 [N][128] (6.4M halfs)
#define O_HLH    11850528    //   800,000  layer-2 features fp16 [N][32] (1.6M halfs)
#define O_ASRC2  12650528    //    50,000  per-node src logits layer2
#define O_ADST2  12700528    //    50,000  per-node dst logits layer2
#define WS_ELEMS 12750528    // ~51 MB

#define NODES_PER_GRP (NN / 8)                               // 6250 (NN % 8 == 0)

// ------ fused: edge_attr sum + degree count (real edges only) + coef precompute -------
__global__ void k_ea_count(const float* __restrict__ ea, const int* __restrict__ ei,
                           const float* __restrict__ lew1, const float* __restrict__ ae1,
                           const float* __restrict__ lew2, const float* __restrict__ ae2,
                           float* __restrict__ easum, int* __restrict__ deg,
                           float* __restrict__ coef) {
  // block 0, threads 0-127: edge-coef dot products (tiny, overlapped with edge loop)
  if (blockIdx.x == 0 && threadIdx.x < 128) {
    int t = threadIdx.x;
    float p = lew1[t] * ae1[t];
    #pragma unroll
    for (int o = 16; o > 0; o >>= 1) p += __shfl_down(p, o, 32);
    if ((t & 31) == 0) coef[t >> 5] = p;
    if (t < 32) {
      float q = lew2[t] * ae2[t];
      #pragma unroll
      for (int o = 16; o > 0; o >>= 1) q += __shfl_down(q, o, 32);
      if (t == 0) coef[4] = q;
    }
  }
  __shared__ float red[4];
  float s = 0.f;
  int stride = gridDim.x * blockDim.x;
  for (int i = blockIdx.x * blockDim.x + threadIdx.x; i < EE; i += stride) {
    s += ea[i];
    atomicAdd(deg + ei[EE + i], 1);
  }
  #pragma unroll
  for (int o = 32; o > 0; o >>= 1) s += __shfl_down(s, o, 64);
  if ((threadIdx.x & 63) == 0) red[threadIdx.x >> 6] = s;
  __syncthreads();
  if (threadIdx.x == 0) atomicAdd(easum, red[0] + red[1] + red[2] + red[3]);
}

// -------------------- multi-block exclusive scan of (deg+1) --------------------
__device__ __forceinline__ int wave_incl_scan(int v, int lane) {
  #pragma unroll
  for (int o = 1; o < 64; o <<= 1) {
    int u = __shfl_up(v, o, 64);
    if (lane >= o) v += u;
  }
  return v;
}

__global__ __launch_bounds__(256) void k_scan_blk(const int* __restrict__ deg,
                                                  int* __restrict__ rowptr,
                                                  int* __restrict__ blksum) {
  __shared__ int wsum[4];
  const int t = threadIdx.x;
  const int i = blockIdx.x * 256 + t;
  const int lane = t & 63, wv = t >> 6;
  int v = (i < NN) ? (deg[i] + 1) : 0;       // +1 = self-loop
  int incl = wave_incl_scan(v, lane);
  if (lane == 63) wsum[wv] = incl;
  __syncthreads();
  int off = 0;
  #pragma unroll
  for (int k = 0; k < 4; ++k) if (k < wv) off += wsum[k];
  incl += off;
  if (i < NN) rowptr[i] = incl - v;          // local exclusive
  if (t == 255) blksum[blockIdx.x] = incl;   // block total
}

// fused top-level scan + add: each block reduces blksum[0..bid) itself
// (196 L2-resident ints; no separate 1-block top-scan launch)
__global__ __launch_bounds__(256) void k_scan_add(int* __restrict__ rowptr,
                                                  int* __restrict__ cursor,
                                                  const int* __restrict__ blksum) {
  __shared__ int wsum[4];
  const int t = threadIdx.x;
  int v = (t < SCAN_BLOCKS && t < (int)blockIdx.x) ? blksum[t] : 0;
  #pragma unroll
  for (int o = 32; o > 0; o >>= 1) v += __shfl_down(v, o, 64);
  if ((t & 63) == 0) wsum[t >> 6] = v;
  __syncthreads();
  const int off = wsum[0] + wsum[1] + wsum[2] + wsum[3];
  const int i = blockIdx.x * 256 + t;
  if (i < NN) {
    int r = rowptr[i] + off;
    rowptr[i] = r;
    cursor[i] = r;
  }
  if (i == 0) rowptr[NN] = ETOT;
}

// fill CSR slots, XCD-partitioned by dst range (round-7 verified). Round-13:
// do NOT fuse with lin1 — same-grid fusion serializes by dispatch order.
#define FILL_CHUNK  2048
#define FILL_NCHUNK ((ETOT + FILL_CHUNK - 1) / FILL_CHUNK)   // 416
__global__ __launch_bounds__(256) void k_fill(
    const int* __restrict__ ei, const float* __restrict__ eattr,
    const float* __restrict__ easum, int* __restrict__ cursor,
    unsigned* __restrict__ slot) {
  const int g    = blockIdx.x & 7;            // dst group == XCD (heuristic)
  const int c    = blockIdx.x >> 3;           // edge chunk
  const int dlo  = g * NODES_PER_GRP;
  const int dhi  = dlo + NODES_PER_GRP;
  const int base = c * FILL_CHUNK;
  #pragma unroll
  for (int it = 0; it < FILL_CHUNK / 256; ++it) {
    const int e = base + it * 256 + threadIdx.x;
    if (e < ETOT) {
      int d = (e < EE) ? ei[EE + e] : (e - EE);
      if (d >= dlo && d < dhi) {
        int s; float ea;
        if (e < EE) { s = ei[e]; ea = eattr[e]; }
        else { s = d; ea = easum[0] * (1.f / EE); }
        int sl = atomicAdd(cursor + d, 1);
        unsigned hb = (unsigned)__half_as_ushort(__float2half_rn(ea));
        slot[sl] = (unsigned)s | (hb << 16);
      }
    }
  }
}

// 32 FMAs against one uniform W row of 32 floats
#define GEMM_STEP(WB, K, XS) {                                              \
    const float4* Wr = (const float4*)((WB) + (size_t)(K));                 \
    _Pragma("unroll")                                                       \
    for (int j4 = 0; j4 < 8; ++j4) {                                        \
      float4 wv = Wr[j4];                                                   \
      acc[j4 * 4 + 0] += (XS) * wv.x;                                       \
      acc[j4 * 4 + 1] += (XS) * wv.y;                                       \
      acc[j4 * 4 + 2] += (XS) * wv.z;                                       \
      acc[j4 * 4 + 3] += (XS) * wv.w;                                       \
    } }

// -------------------- layer-1 GEMM: xl(fp16) = x @ W1, plus per-node logits -------------
// Round-8 lesson: h must be PROVABLY scalar (readfirstlane) so W reads stay s_load.
#define L1_NB ((NN + 63) / 64)      // 782 node-blocks
__global__ __launch_bounds__(256) void k_lin1(
    const float* __restrict__ x, const float* __restrict__ W,
    const float* __restrict__ att_src, const float* __restrict__ att_dst,
    __half* __restrict__ xlh, float* __restrict__ asrc, float* __restrict__ adst) {
  const int h   = __builtin_amdgcn_readfirstlane(threadIdx.x >> 6);  // SGPR head id
  const int n   = blockIdx.x * 64 + (threadIdx.x & 63);
  const int nc  = n < NN ? n : NN - 1;
  const float4* xr = (const float4*)(x + (size_t)nc * 128);
  const float*  Wh = W + h * 32;              // scalar base -> s_load W rows
  float acc[32];
  #pragma unroll
  for (int j = 0; j < 32; ++j) acc[j] = 0.f;
  float4 xv = xr[0];
  for (int kt = 0; kt < 32; ++kt) {
    float4 cur = xv;
    if (kt < 31) xv = xr[kt + 1];             // prefetch next 16B of x
    GEMM_STEP(Wh, (kt * 4 + 0) * 128, cur.x);
    GEMM_STEP(Wh, (kt * 4 + 1) * 128, cur.y);
    GEMM_STEP(Wh, (kt * 4 + 2) * 128, cur.z);
    GEMM_STEP(Wh, (kt * 4 + 3) * 128, cur.w);
  }
  if (n < NN) {
    __align__(16) __half hbuf[32];
    #pragma unroll
    for (int j = 0; j < 32; ++j) hbuf[j] = __float2half_rn(acc[j]);
    float4* dst = (float4*)(xlh + (size_t)n * 128 + h * 32);   // 64 B, 16B-aligned
    #pragma unroll
    for (int i = 0; i < 4; ++i) dst[i] = ((const float4*)hbuf)[i];
    float ss = 0.f, sd = 0.f;
    #pragma unroll
    for (int j = 0; j < 32; ++j) {
      ss += acc[j] * att_src[h * 32 + j];     // scalar loads
      sd += acc[j] * att_dst[h * 32 + j];
    }
    asrc[n * 4 + h] = ss;
    adst[n * 4 + h] = sd;
  }
}

// --------- FUSED: layer-1 aggregation + layer-2 GEMM (lin2 folded in) ---------
// Round-15 verified: fusion works (total 290.5->283.4; out1 traffic gone). PMC:
// 70 us, VALU 48%, Occ 71%, FETCH 92 MB @1.4 TB/s -> gather-LATENCY-bound (below
// both VALU and fill-BW ceilings). This round: batch-4 -> batch-8 gather pipeline
// (8 outstanding row-gathers per half-wave; Guideline 7 ILP). VGPR headroom: 24.
__global__ __launch_bounds__(256) void k_agg1l2(
    const int* __restrict__ rowptr, const unsigned* __restrict__ slot,
    const float* __restrict__ asrc, const float* __restrict__ adst,
    const float* __restrict__ coef, const __half* __restrict__ xlh,
    const float* __restrict__ bias1, const float* __restrict__ W2,
    const float* __restrict__ as2w, const float* __restrict__ ad2w,
    __half* __restrict__ hlh, float* __restrict__ asrc2, float* __restrict__ adst2) {
  __shared__ float rowbuf[8][132];    // +4 pad
  int nl = threadIdx.x >> 5;          // node slot in block (0..7)
  int n = blockIdx.x * 8 + nl;
  if (n >= NN) return;
  int l = threadIdx.x & 31;
  int c4 = l << 2;                    // 4 channels per lane, 32 lanes = 128 ch
  int h = l >> 3;                     // head of this channel group
  float cf = coef[h];
  float ad = adst[(size_t)n * 4 + h];
  int r0 = rowptr[n], r1 = rowptr[n + 1];   // r1 > r0 (self-loop)
  float a0 = 0.f, a1 = 0.f, a2 = 0.f, a3 = 0.f, den = 0.f;
  for (int j = r0; j < r1; j += 8) {
    unsigned sd[8]; float asv[8]; uint2 raw[8];
    #pragma unroll
    for (int k = 0; k < 8; ++k) {
      int jj = (j + k < r1) ? (j + k) : (r1 - 1);
      sd[k] = slot[jj];
    }
    #pragma unroll
    for (int k = 0; k < 8; ++k) {
      int sn = (int)(sd[k] & 0xFFFFu);
      asv[k] = asrc[(size_t)sn * 4 + h];
      raw[k] = *(const uint2*)(xlh + (size_t)sn * 128 + c4);   // 4 halfs
    }
    #pragma unroll
    for (int k = 0; k < 8; ++k) {
      float eav = __half2float(__ushort_as_half((unsigned short)(sd[k] >> 16)));
      float alpha = asv[k] + ad + eav * cf;
      alpha = alpha > 0.f ? alpha : NEG * alpha;
      float ex = (j + k < r1) ? __expf(alpha) : 0.f;   // tail mask
      __half2 p0, p1;
      *(unsigned int*)&p0 = raw[k].x;
      *(unsigned int*)&p1 = raw[k].y;
      float2 f0 = __half22float2(p0), f1 = __half22float2(p1);
      a0 += ex * f0.x;
      a1 += ex * f0.y;
      a2 += ex * f1.x;
      a3 += ex * f1.y;
      den += ex;
    }
  }
  float inv = 1.f / den;
  // ELU(row + bias1) -> LDS (wave-synchronous: same wave writes then reads)
  float4 b = *(const float4*)(bias1 + c4);
  float v0 = a0 * inv + b.x, v1 = a1 * inv + b.y;
  float v2 = a2 * inv + b.z, v3 = a3 * inv + b.w;
  v0 = v0 > 0.f ? v0 : (expf(v0) - 1.f);
  v1 = v1 > 0.f ? v1 : (expf(v1) - 1.f);
  v2 = v2 > 0.f ? v2 : (expf(v2) - 1.f);
  v3 = v3 > 0.f ? v3 : (expf(v3) - 1.f);
  rowbuf[nl][c4 + 0] = v0;
  rowbuf[nl][c4 + 1] = v1;
  rowbuf[nl][c4 + 2] = v2;
  rowbuf[nl][c4 + 3] = v3;
  // layer-2 GEMM: lane = output col; row broadcast from LDS, W2 L1-resident
  const int col = l;
  const float* rw = rowbuf[nl];
  float hsum = 0.f;
  #pragma unroll 4
  for (int k = 0; k < 128; ++k) hsum += rw[k] * W2[k * 32 + col];
  hlh[(size_t)n * 32 + col] = __float2half_rn(hsum);
  float ps = hsum * as2w[col];
  float pd = hsum * ad2w[col];
  #pragma unroll
  for (int o = 1; o < 32; o <<= 1) {   // xor<32 stays within the half-wave
    ps += __shfl_xor(ps, o, 64);
    pd += __shfl_xor(pd, o, 64);
  }
  if (l == 0) {
    asrc2[n] = ps;
    adst2[n] = pd;
  }
}

// -------------------- layer-2 aggregation (fused softmax), batch-4 pipelined ------------
__global__ __launch_bounds__(256) void k_agg2(
    const int* __restrict__ rowptr, const unsigned* __restrict__ slot,
    const float* __restrict__ asrc2, const float* __restrict__ adst2,
    const float* __restrict__ coef, const __half* __restrict__ hlh,
    const float* __restrict__ bias2, float* __restrict__ out) {
  int n = blockIdx.x * 32 + (threadIdx.x >> 3);
  if (n >= NN) return;
  int c4 = (threadIdx.x & 7) << 2;
  float cf = coef[4];
  float ad = adst2[n];
  int r0 = rowptr[n], r1 = rowptr[n + 1];
  float a0 = 0.f, a1 = 0.f, a2 = 0.f, a3 = 0.f, den = 0.f;
  for (int j = r0; j < r1; j += 4) {
    unsigned sd[4]; float asv[4]; uint2 raw[4];
    #pragma unroll
    for (int k = 0; k < 4; ++k) {
      int jj = (j + k < r1) ? (j + k) : (r1 - 1);
      sd[k] = slot[jj];
    }
    #pragma unroll
    for (int k = 0; k < 4; ++k) {
      int sn = (int)(sd[k] & 0xFFFFu);
      asv[k] = asrc2[sn];
      raw[k] = *(const uint2*)(hlh + (size_t)sn * 32 + c4);   // 4 halfs
    }
    #pragma unroll
    for (int k = 0; k < 4; ++k) {
      float eav = __half2float(__ushort_as_half((unsigned short)(sd[k] >> 16)));
      float alpha = asv[k] + ad + eav * cf;
      alpha = alpha > 0.f ? alpha : NEG * alpha;
      float ex = (j + k < r1) ? __expf(alpha) : 0.f;   // tail mask
      __half2 p0, p1;
      *(unsigned int*)&p0 = raw[k].x;
      *(unsigned int*)&p1 = raw[k].y;
      float2 f0 = __half22float2(p0), f1 = __half22float2(p1);
      a0 += ex * f0.x;
      a1 += ex * f0.y;
      a2 += ex * f1.x;
      a3 += ex * f1.y;
      den += ex;
    }
  }
  float inv = 1.f / den;
  float4 b = *(const float4*)(bias2 + c4);
  *(float4*)(out + (size_t)n * 32 + c4) =
      make_float4(a0 * inv + b.x, a1 * inv + b.y, a2 * inv + b.z, a3 * inv + b.w);
}

extern "C" void kernel_launch(void* const* d_in, const int* in_sizes, int n_in,
                              void* d_out, int out_size, void* d_ws, size_t ws_size,
                              hipStream_t stream) {
  const float* x        = (const float*)d_in[0];
  const int*   ei       = (const int*)d_in[1];
  const float* eattr    = (const float*)d_in[2];
  const float* lin1_w   = (const float*)d_in[3];
  const float* att1_src = (const float*)d_in[4];
  const float* att1_dst = (const float*)d_in[5];
  const float* lin1_ew  = (const float*)d_in[6];
  const float* att1_e   = (const float*)d_in[7];
  const float* bias1    = (const float*)d_in[8];
  const float* lin2_w   = (const float*)d_in[9];
  const float* att2_src = (const float*)d_in[10];
  const float* att2_dst = (const float*)d_in[11];
  const float* lin2_ew  = (const float*)d_in[12];
  const float* att2_e   = (const float*)d_in[13];
  const float* bias2    = (const float*)d_in[14];
  float* out = (float*)d_out;
  float* ws  = (float*)d_ws;
  int*   wsi = (int*)d_ws;

  int*      deg     = wsi + O_DEG;
  float*    easum   = ws + O_EASUM;
  float*    coef    = ws + O_COEF;
  int*      rowptr  = wsi + O_ROWPTR;
  int*      cursor  = wsi + O_CURSOR;
  int*      blksum  = wsi + O_BLKSUM;
  unsigned* slot    = (unsigned*)(ws + O_SLOT);
  float*    asrc1   = ws + O_ASRC1;
  float*    adst1   = ws + O_ADST1;
  __half*   xlh     = (__half*)(ws + O_XLH);
  __half*   hlh     = (__half*)(ws + O_HLH);
  float*    asrc2   = ws + O_ASRC2;
  float*    adst2   = ws + O_ADST2;

  // zero deg/easum (ws poisoned 0xAA each call)
  hipMemsetAsync(ws, 0, (size_t)ZERO_ELEMS * sizeof(float), stream);

  k_ea_count<<<256, 256, 0, stream>>>(eattr, ei, lin1_ew, att1_e, lin2_ew, att2_e,
                                      easum, deg, coef);

  // CSR build (dst-sorted): multi-block scan (top-level scan fused into add)
  k_scan_blk<<<SCAN_BLOCKS, 256, 0, stream>>>(deg, rowptr, blksum);
  k_scan_add<<<SCAN_BLOCKS, 256, 0, stream>>>(rowptr, cursor, blksum);
  k_fill<<<FILL_NCHUNK * 8, 256, 0, stream>>>(ei, eattr, easum, cursor, slot);

  // layer 1
  k_lin1<<<L1_NB, 256, 0, stream>>>(x, lin1_w, att1_src, att1_dst, xlh, asrc1, adst1);

  // fused layer-1 aggregation + layer-2 GEMM (out1 never materialized)
  k_agg1l2<<<(NN + 7) / 8, 256, 0, stream>>>(rowptr, slot, asrc1, adst1, coef, xlh,
                                             bias1, lin2_w, att2_src, att2_dst,
                                             hlh, asrc2, adst2);

  k_agg2<<<(NN + 31) / 32, 256, 0, stream>>>(rowptr, slot, asrc2, adst2, coef, hlh, bias2, out);
}